// Round 5
// baseline (106.848 us; speedup 1.0000x reference)
//
#include <hip/hip_runtime.h>
#include <math.h>

#define BB 4
#define CC 248
#define TT 500
#define DD 64
#define NQ (CC * CC / 4)   // 15376 float4 quads per (b,t) tile

typedef float f32x4 __attribute__((ext_vector_type(4)));

__global__ __launch_bounds__(256) void csa_kernel(
    const float* __restrict__ x,
    const float* __restrict__ wq, const float* __restrict__ bq,
    const float* __restrict__ wk, const float* __restrict__ bk,
    const float* __restrict__ wv, const float* __restrict__ bv,
    float* __restrict__ out, float* __restrict__ wts)
{
    const int bt = blockIdx.x;          // 0 .. B*T-1
    const int b  = bt / TT;
    const int t  = bt % TT;
    const int tid  = threadIdx.x;
    const int wave = tid >> 6;
    const int lane = tid & 63;

    __shared__ __align__(16) float xs[CC];
    __shared__ __align__(16) f32x4 sRowV[CC];   // {s2, -m2, inv, 0} per row
    __shared__ float sred[8];
    __shared__ float sA, sB2, sXmax, sXmin, sYbar;

    // ---- load x slice: x[b, c, t] ----
    if (tid < CC) xs[tid] = x[((size_t)b * CC + tid) * TT + t];

    // ---- wave 1: a = wq.wk/8, b2 = bq.wk/8 ----
    if (wave == 1) {
        float wkv = wk[lane];
        float pa = wq[lane] * wkv;
        float pb = bq[lane] * wkv;
        #pragma unroll
        for (int off = 32; off > 0; off >>= 1) {
            pa += __shfl_xor(pa, off, 64);
            pb += __shfl_xor(pb, off, 64);
        }
        if (lane == 0) { sA = pa * 0.125f; sB2 = pb * 0.125f; }
    }
    __syncthreads();

    // ---- block reduce xmax / xmin ----
    float vmax = -INFINITY, vmin = INFINITY;
    if (tid < CC) { vmax = xs[tid]; vmin = vmax; }
    #pragma unroll
    for (int off = 32; off > 0; off >>= 1) {
        vmax = fmaxf(vmax, __shfl_xor(vmax, off, 64));
        vmin = fminf(vmin, __shfl_xor(vmin, off, 64));
    }
    if (lane == 0) { sred[wave] = vmax; sred[4 + wave] = vmin; }
    __syncthreads();
    if (tid == 0) {
        sXmax = fmaxf(fmaxf(sred[0], sred[1]), fmaxf(sred[2], sred[3]));
        sXmin = fminf(fminf(sred[4], sred[5]), fminf(sred[6], sred[7]));
    }
    __syncthreads();

    const float LOG2E = 1.4426950408889634f;
    const float a2   = sA  * LOG2E;      // p = exp2(s2*x_e - m2)
    const float b22  = sB2 * LOG2E;
    const float xmax = sXmax;
    const float xmin = sXmin;
    const f32x4* xs4 = reinterpret_cast<const f32x4*>(xs);

    // ============ PHASE A: thread-per-row params, zero cross-lane ops ========
    const int  r      = tid;
    const bool rowact = (r < CC);
    const float xr = rowact ? xs[r] : 0.f;
    const float s2 = fmaf(a2, xr, b22);
    const float m2 = (s2 >= 0.f) ? s2 * xmax : s2 * xmin;

    float d0 = 0.f, d1 = 0.f, d2 = 0.f, d3 = 0.f;
    float p0 = 0.f, p1 = 0.f, p2 = 0.f, p3 = 0.f;
    #pragma unroll 2
    for (int j = 0; j < CC / 4; ++j) {
        const f32x4 xv = xs4[j];                    // broadcast read
        const float e0 = __builtin_amdgcn_exp2f(fmaf(s2, xv.x, -m2));
        const float e1 = __builtin_amdgcn_exp2f(fmaf(s2, xv.y, -m2));
        const float e2 = __builtin_amdgcn_exp2f(fmaf(s2, xv.z, -m2));
        const float e3 = __builtin_amdgcn_exp2f(fmaf(s2, xv.w, -m2));
        d0 += e0; d1 += e1; d2 += e2; d3 += e3;
        p0 = fmaf(e0, xv.x, p0); p1 = fmaf(e1, xv.y, p1);
        p2 = fmaf(e2, xv.z, p2); p3 = fmaf(e3, xv.w, p3);
    }
    const float denom = (d0 + d1) + (d2 + d3);
    const float xp    = (p0 + p1) + (p2 + p3);
    const float inv   = __builtin_amdgcn_rcpf(denom);
    if (rowact) {
        f32x4 prm; prm.x = s2; prm.y = -m2; prm.z = inv; prm.w = 0.f;
        sRowV[r] = prm;
    }

    // ---- ybar = mean_r (xp_r * inv_r) ----
    float yr = rowact ? xp * inv : 0.f;
    #pragma unroll
    for (int off = 32; off > 0; off >>= 1) yr += __shfl_xor(yr, off, 64);
    if (lane == 0) sred[wave] = yr;
    __syncthreads();
    if (tid == 0)
        sYbar = (sred[0] + sred[1] + sred[2] + sred[3]) * (1.0f / CC);
    __syncthreads();   // sRowV + sYbar ready

    // out store early (not in the tail)
    if (tid < DD)
        out[(size_t)bt * DD + tid] = fmaf(wv[tid], sYbar, bv[tid]);

    // ============ PHASE B: streaming nontemporal stores =======================
    f32x4* wq4 = reinterpret_cast<f32x4*>(wts + (size_t)bt * (CC * CC));

    #pragma unroll 4
    for (int it = 0; it < NQ / 256; ++it) {         // 60 full iterations
        const int idx = it * 256 + tid;
        const int row = idx / 62;                   // magic-mul
        const int c4  = idx - row * 62;
        const f32x4 prm = sRowV[row];
        const f32x4 xv  = xs4[c4];
        f32x4 o;
        o.x = __builtin_amdgcn_exp2f(fmaf(prm.x, xv.x, prm.y)) * prm.z;
        o.y = __builtin_amdgcn_exp2f(fmaf(prm.x, xv.y, prm.y)) * prm.z;
        o.z = __builtin_amdgcn_exp2f(fmaf(prm.x, xv.z, prm.y)) * prm.z;
        o.w = __builtin_amdgcn_exp2f(fmaf(prm.x, xv.w, prm.y)) * prm.z;
        __builtin_nontemporal_store(o, &wq4[idx]);
    }
    {   // tail: 15376 - 60*256 = 16 quads
        const int idx = (NQ / 256) * 256 + tid;
        if (tid < NQ - (NQ / 256) * 256) {
            const int row = idx / 62;
            const int c4  = idx - row * 62;
            const f32x4 prm = sRowV[row];
            const f32x4 xv  = xs4[c4];
            f32x4 o;
            o.x = __builtin_amdgcn_exp2f(fmaf(prm.x, xv.x, prm.y)) * prm.z;
            o.y = __builtin_amdgcn_exp2f(fmaf(prm.x, xv.y, prm.y)) * prm.z;
            o.z = __builtin_amdgcn_exp2f(fmaf(prm.x, xv.z, prm.y)) * prm.z;
            o.w = __builtin_amdgcn_exp2f(fmaf(prm.x, xv.w, prm.y)) * prm.z;
            __builtin_nontemporal_store(o, &wq4[idx]);
        }
    }
}

extern "C" void kernel_launch(void* const* d_in, const int* in_sizes, int n_in,
                              void* d_out, int out_size, void* d_ws, size_t ws_size,
                              hipStream_t stream) {
    const float* x  = (const float*)d_in[0];
    const float* wq = (const float*)d_in[1];
    const float* bq = (const float*)d_in[2];
    const float* wk = (const float*)d_in[3];
    const float* bk = (const float*)d_in[4];
    const float* wv = (const float*)d_in[5];
    const float* bv = (const float*)d_in[6];

    float* out = (float*)d_out;                          // [B,T,D]
    float* wts = (float*)d_out + (size_t)BB * TT * DD;   // [B,T,C,C]

    // 40 KB dynamic LDS pad (unreferenced, reserved at dispatch): static ~5 KB
    // + 40 KB => ~45 KB/block => 3 blocks/CU resident (768 of 2000). Queued
    // blocks' phase A (VALU) overlaps resident blocks' store drain.
    const size_t dynLds = 40 * 1024;
    csa_kernel<<<dim3(BB * TT), dim3(256), dynLds, stream>>>(x, wq, bq, wk, bk, wv, bv, out, wts);
}

// Round 6
// 106.521 us; speedup vs baseline: 1.0031x; 1.0031x over previous
//
#include <hip/hip_runtime.h>
#include <math.h>

#define BB 4
#define CC 248
#define TT 500
#define DD 64
#define NQ (CC * CC / 4)   // 15376 float4 quads per (b,t) tile

typedef float f32x4 __attribute__((ext_vector_type(4)));

__global__ __launch_bounds__(256) void csa_kernel(
    const float* __restrict__ x,
    const float* __restrict__ wq, const float* __restrict__ bq,
    const float* __restrict__ wk, const float* __restrict__ bk,
    const float* __restrict__ wv, const float* __restrict__ bv,
    float* __restrict__ out, float* __restrict__ wts)
{
    const int bt = blockIdx.x;          // 0 .. B*T-1
    const int b  = bt / TT;
    const int t  = bt % TT;
    const int tid  = threadIdx.x;
    const int wave = tid >> 6;
    const int lane = tid & 63;

    __shared__ __align__(16) float xs[CC];
    __shared__ __align__(16) f32x4 sRowV[CC];   // {s2, -m2, inv, 0} per row
    __shared__ float sred[8];
    __shared__ float sA, sB2, sXmax, sXmin, sYbar;

    // ---- load x slice: x[b, c, t] ----
    if (tid < CC) xs[tid] = x[((size_t)b * CC + tid) * TT + t];

    // ---- wave 1: a = wq.wk/8, b2 = bq.wk/8 ----
    if (wave == 1) {
        float wkv = wk[lane];
        float pa = wq[lane] * wkv;
        float pb = bq[lane] * wkv;
        #pragma unroll
        for (int off = 32; off > 0; off >>= 1) {
            pa += __shfl_xor(pa, off, 64);
            pb += __shfl_xor(pb, off, 64);
        }
        if (lane == 0) { sA = pa * 0.125f; sB2 = pb * 0.125f; }
    }
    __syncthreads();

    // ---- block reduce xmax / xmin ----
    float vmax = -INFINITY, vmin = INFINITY;
    if (tid < CC) { vmax = xs[tid]; vmin = vmax; }
    #pragma unroll
    for (int off = 32; off > 0; off >>= 1) {
        vmax = fmaxf(vmax, __shfl_xor(vmax, off, 64));
        vmin = fminf(vmin, __shfl_xor(vmin, off, 64));
    }
    if (lane == 0) { sred[wave] = vmax; sred[4 + wave] = vmin; }
    __syncthreads();
    if (tid == 0) {
        sXmax = fmaxf(fmaxf(sred[0], sred[1]), fmaxf(sred[2], sred[3]));
        sXmin = fminf(fminf(sred[4], sred[5]), fminf(sred[6], sred[7]));
    }
    __syncthreads();

    const float LOG2E = 1.4426950408889634f;
    const float a2   = sA  * LOG2E;      // p = exp2(s2*x_e - m2)
    const float b22  = sB2 * LOG2E;
    const float xmax = sXmax;
    const float xmin = sXmin;
    const f32x4* xs4 = reinterpret_cast<const f32x4*>(xs);

    // ============ PHASE A: thread-per-row params, zero cross-lane ops ========
    const int  r      = tid;
    const bool rowact = (r < CC);
    const float xr = rowact ? xs[r] : 0.f;
    const float s2 = fmaf(a2, xr, b22);
    const float m2 = (s2 >= 0.f) ? s2 * xmax : s2 * xmin;

    float d0 = 0.f, d1 = 0.f, d2 = 0.f, d3 = 0.f;
    float p0 = 0.f, p1 = 0.f, p2 = 0.f, p3 = 0.f;
    #pragma unroll 2
    for (int j = 0; j < CC / 4; ++j) {
        const f32x4 xv = xs4[j];                    // broadcast read
        const float e0 = __builtin_amdgcn_exp2f(fmaf(s2, xv.x, -m2));
        const float e1 = __builtin_amdgcn_exp2f(fmaf(s2, xv.y, -m2));
        const float e2 = __builtin_amdgcn_exp2f(fmaf(s2, xv.z, -m2));
        const float e3 = __builtin_amdgcn_exp2f(fmaf(s2, xv.w, -m2));
        d0 += e0; d1 += e1; d2 += e2; d3 += e3;
        p0 = fmaf(e0, xv.x, p0); p1 = fmaf(e1, xv.y, p1);
        p2 = fmaf(e2, xv.z, p2); p3 = fmaf(e3, xv.w, p3);
    }
    const float denom = (d0 + d1) + (d2 + d3);
    const float xp    = (p0 + p1) + (p2 + p3);
    const float inv   = __builtin_amdgcn_rcpf(denom);
    if (rowact) {
        f32x4 prm; prm.x = s2; prm.y = -m2; prm.z = inv; prm.w = 0.f;
        sRowV[r] = prm;
    }

    // ---- ybar = mean_r (xp_r * inv_r) ----
    float yr = rowact ? xp * inv : 0.f;
    #pragma unroll
    for (int off = 32; off > 0; off >>= 1) yr += __shfl_xor(yr, off, 64);
    if (lane == 0) sred[wave] = yr;
    __syncthreads();
    if (tid == 0)
        sYbar = (sred[0] + sred[1] + sred[2] + sred[3]) * (1.0f / CC);
    __syncthreads();   // sRowV + sYbar ready

    // out store early (not in the tail)
    if (tid < DD)
        out[(size_t)bt * DD + tid] = fmaf(wv[tid], sYbar, bv[tid]);

    // ============ PHASE B: streaming nontemporal stores =======================
    f32x4* wq4 = reinterpret_cast<f32x4*>(wts + (size_t)bt * (CC * CC));

    #pragma unroll 4
    for (int it = 0; it < NQ / 256; ++it) {         // 60 full iterations
        const int idx = it * 256 + tid;
        const int row = idx / 62;                   // magic-mul
        const int c4  = idx - row * 62;
        const f32x4 prm = sRowV[row];
        const f32x4 xv  = xs4[c4];
        f32x4 o;
        o.x = __builtin_amdgcn_exp2f(fmaf(prm.x, xv.x, prm.y)) * prm.z;
        o.y = __builtin_amdgcn_exp2f(fmaf(prm.x, xv.y, prm.y)) * prm.z;
        o.z = __builtin_amdgcn_exp2f(fmaf(prm.x, xv.z, prm.y)) * prm.z;
        o.w = __builtin_amdgcn_exp2f(fmaf(prm.x, xv.w, prm.y)) * prm.z;
        __builtin_nontemporal_store(o, &wq4[idx]);
    }
    {   // tail: 15376 - 60*256 = 16 quads
        const int idx = (NQ / 256) * 256 + tid;
        if (tid < NQ - (NQ / 256) * 256) {
            const int row = idx / 62;
            const int c4  = idx - row * 62;
            const f32x4 prm = sRowV[row];
            const f32x4 xv  = xs4[c4];
            f32x4 o;
            o.x = __builtin_amdgcn_exp2f(fmaf(prm.x, xv.x, prm.y)) * prm.z;
            o.y = __builtin_amdgcn_exp2f(fmaf(prm.x, xv.y, prm.y)) * prm.z;
            o.z = __builtin_amdgcn_exp2f(fmaf(prm.x, xv.z, prm.y)) * prm.z;
            o.w = __builtin_amdgcn_exp2f(fmaf(prm.x, xv.w, prm.y)) * prm.z;
            __builtin_nontemporal_store(o, &wq4[idx]);
        }
    }
}

extern "C" void kernel_launch(void* const* d_in, const int* in_sizes, int n_in,
                              void* d_out, int out_size, void* d_ws, size_t ws_size,
                              hipStream_t stream) {
    const float* x  = (const float*)d_in[0];
    const float* wq = (const float*)d_in[1];
    const float* bq = (const float*)d_in[2];
    const float* wk = (const float*)d_in[3];
    const float* bk = (const float*)d_in[4];
    const float* wv = (const float*)d_in[5];
    const float* bv = (const float*)d_in[6];

    float* out = (float*)d_out;                          // [B,T,D]
    float* wts = (float*)d_out + (size_t)BB * TT * DD;   // [B,T,C,C]

    // 40 KB dynamic LDS pad (unreferenced, reserved at dispatch): static ~5 KB
    // + 40 KB => ~45 KB/block => 3 blocks/CU resident (768 of 2000). Queued
    // blocks' phase A (VALU) overlaps resident blocks' store drain.
    const size_t dynLds = 40 * 1024;
    csa_kernel<<<dim3(BB * TT), dim3(256), dynLds, stream>>>(x, wq, bq, wk, bk, wv, bv, out, wts);
}

// Round 7
// 106.233 us; speedup vs baseline: 1.0058x; 1.0027x over previous
//
#include <hip/hip_runtime.h>
#include <math.h>

#define BB 4
#define CC 248
#define TT 500
#define DD 64
#define NQ (CC * CC / 4)   // 15376 float4 quads per (b,t) tile

typedef float f32x4 __attribute__((ext_vector_type(4)));

__global__ __launch_bounds__(256) void csa_kernel(
    const float* __restrict__ x,
    const float* __restrict__ wq, const float* __restrict__ bq,
    const float* __restrict__ wk, const float* __restrict__ bk,
    const float* __restrict__ wv, const float* __restrict__ bv,
    float* __restrict__ out, float* __restrict__ wts)
{
    const int bt = blockIdx.x;          // 0 .. B*T-1
    const int b  = bt / TT;
    const int t  = bt % TT;
    const int tid  = threadIdx.x;
    const int wave = tid >> 6;
    const int lane = tid & 63;

    __shared__ __align__(16) float xs[CC];
    __shared__ __align__(16) f32x4 sRowV[CC];   // {s2, -m2, inv, 0} per row
    __shared__ float sred[8];
    __shared__ float sA, sB2, sXmax, sXmin, sYbar;

    // ---- load x slice: x[b, c, t] ----
    if (tid < CC) xs[tid] = x[((size_t)b * CC + tid) * TT + t];

    // ---- wave 1: a = wq.wk/8, b2 = bq.wk/8 ----
    if (wave == 1) {
        float wkv = wk[lane];
        float pa = wq[lane] * wkv;
        float pb = bq[lane] * wkv;
        #pragma unroll
        for (int off = 32; off > 0; off >>= 1) {
            pa += __shfl_xor(pa, off, 64);
            pb += __shfl_xor(pb, off, 64);
        }
        if (lane == 0) { sA = pa * 0.125f; sB2 = pb * 0.125f; }
    }
    __syncthreads();

    // ---- block reduce xmax / xmin ----
    float vmax = -INFINITY, vmin = INFINITY;
    if (tid < CC) { vmax = xs[tid]; vmin = vmax; }
    #pragma unroll
    for (int off = 32; off > 0; off >>= 1) {
        vmax = fmaxf(vmax, __shfl_xor(vmax, off, 64));
        vmin = fminf(vmin, __shfl_xor(vmin, off, 64));
    }
    if (lane == 0) { sred[wave] = vmax; sred[4 + wave] = vmin; }
    __syncthreads();
    if (tid == 0) {
        sXmax = fmaxf(fmaxf(sred[0], sred[1]), fmaxf(sred[2], sred[3]));
        sXmin = fminf(fminf(sred[4], sred[5]), fminf(sred[6], sred[7]));
    }
    __syncthreads();

    const float LOG2E = 1.4426950408889634f;
    const float a2   = sA  * LOG2E;      // p = exp2(s2*x_e - m2)
    const float b22  = sB2 * LOG2E;
    const float xmax = sXmax;
    const float xmin = sXmin;
    const f32x4* xs4 = reinterpret_cast<const f32x4*>(xs);

    // ============ PHASE A: thread-per-row params, zero cross-lane ops ========
    const int  r      = tid;
    const bool rowact = (r < CC);
    const float xr = rowact ? xs[r] : 0.f;
    const float s2 = fmaf(a2, xr, b22);
    const float m2 = (s2 >= 0.f) ? s2 * xmax : s2 * xmin;

    float d0 = 0.f, d1 = 0.f, d2 = 0.f, d3 = 0.f;
    float p0 = 0.f, p1 = 0.f, p2 = 0.f, p3 = 0.f;
    #pragma unroll 2
    for (int j = 0; j < CC / 4; ++j) {
        const f32x4 xv = xs4[j];                    // broadcast read
        const float e0 = __builtin_amdgcn_exp2f(fmaf(s2, xv.x, -m2));
        const float e1 = __builtin_amdgcn_exp2f(fmaf(s2, xv.y, -m2));
        const float e2 = __builtin_amdgcn_exp2f(fmaf(s2, xv.z, -m2));
        const float e3 = __builtin_amdgcn_exp2f(fmaf(s2, xv.w, -m2));
        d0 += e0; d1 += e1; d2 += e2; d3 += e3;
        p0 = fmaf(e0, xv.x, p0); p1 = fmaf(e1, xv.y, p1);
        p2 = fmaf(e2, xv.z, p2); p3 = fmaf(e3, xv.w, p3);
    }
    const float denom = (d0 + d1) + (d2 + d3);
    const float xp    = (p0 + p1) + (p2 + p3);
    const float inv   = __builtin_amdgcn_rcpf(denom);
    if (rowact) {
        f32x4 prm; prm.x = s2; prm.y = -m2; prm.z = inv; prm.w = 0.f;
        sRowV[r] = prm;
    }

    // ---- ybar = mean_r (xp_r * inv_r) ----
    float yr = rowact ? xp * inv : 0.f;
    #pragma unroll
    for (int off = 32; off > 0; off >>= 1) yr += __shfl_xor(yr, off, 64);
    if (lane == 0) sred[wave] = yr;
    __syncthreads();
    if (tid == 0)
        sYbar = (sred[0] + sred[1] + sred[2] + sred[3]) * (1.0f / CC);
    __syncthreads();   // sRowV + sYbar ready

    // out store early (not in the tail)
    if (tid < DD)
        out[(size_t)bt * DD + tid] = fmaf(wv[tid], sYbar, bv[tid]);

    // ============ PHASE B: streaming nontemporal stores =======================
    f32x4* wq4 = reinterpret_cast<f32x4*>(wts + (size_t)bt * (CC * CC));

    #pragma unroll 4
    for (int it = 0; it < NQ / 256; ++it) {         // 60 full iterations
        const int idx = it * 256 + tid;
        const int row = idx / 62;                   // magic-mul
        const int c4  = idx - row * 62;
        const f32x4 prm = sRowV[row];
        const f32x4 xv  = xs4[c4];
        f32x4 o;
        o.x = __builtin_amdgcn_exp2f(fmaf(prm.x, xv.x, prm.y)) * prm.z;
        o.y = __builtin_amdgcn_exp2f(fmaf(prm.x, xv.y, prm.y)) * prm.z;
        o.z = __builtin_amdgcn_exp2f(fmaf(prm.x, xv.z, prm.y)) * prm.z;
        o.w = __builtin_amdgcn_exp2f(fmaf(prm.x, xv.w, prm.y)) * prm.z;
        __builtin_nontemporal_store(o, &wq4[idx]);
    }
    {   // tail: 15376 - 60*256 = 16 quads
        const int idx = (NQ / 256) * 256 + tid;
        if (tid < NQ - (NQ / 256) * 256) {
            const int row = idx / 62;
            const int c4  = idx - row * 62;
            const f32x4 prm = sRowV[row];
            const f32x4 xv  = xs4[c4];
            f32x4 o;
            o.x = __builtin_amdgcn_exp2f(fmaf(prm.x, xv.x, prm.y)) * prm.z;
            o.y = __builtin_amdgcn_exp2f(fmaf(prm.x, xv.y, prm.y)) * prm.z;
            o.z = __builtin_amdgcn_exp2f(fmaf(prm.x, xv.z, prm.y)) * prm.z;
            o.w = __builtin_amdgcn_exp2f(fmaf(prm.x, xv.w, prm.y)) * prm.z;
            __builtin_nontemporal_store(o, &wq4[idx]);
        }
    }
}

extern "C" void kernel_launch(void* const* d_in, const int* in_sizes, int n_in,
                              void* d_out, int out_size, void* d_ws, size_t ws_size,
                              hipStream_t stream) {
    const float* x  = (const float*)d_in[0];
    const float* wq = (const float*)d_in[1];
    const float* bq = (const float*)d_in[2];
    const float* wk = (const float*)d_in[3];
    const float* bk = (const float*)d_in[4];
    const float* wv = (const float*)d_in[5];
    const float* bv = (const float*)d_in[6];

    float* out = (float*)d_out;                          // [B,T,D]
    float* wts = (float*)d_out + (size_t)BB * TT * DD;   // [B,T,C,C]

    // 40 KB dynamic LDS pad (unreferenced, reserved at dispatch): static ~5 KB
    // + 40 KB => ~45 KB/block => 3 blocks/CU resident (768 of 2000). Queued
    // blocks' phase A (VALU) overlaps resident blocks' store drain.
    const size_t dynLds = 40 * 1024;
    csa_kernel<<<dim3(BB * TT), dim3(256), dynLds, stream>>>(x, wq, bq, wk, bk, wv, bv, out, wts);
}